// Round 7
// baseline (408.379 us; speedup 1.0000x reference)
//
#include <hip/hip_runtime.h>
#include <hip/hip_cooperative_groups.h>

// segment_sum, fully fused: zero-cursor | scatter-to-buckets | gather,
// one cooperative kernel, grid.sync() between phases.
// E = 1M edges, D = 64 f32 features, N = 100K nodes.
//
// ws ints: cursor[N] | ovf_cnt(+3 pad) | ovf[2*OVF_CAP] | bucket[N*CAP]

namespace cg = cooperative_groups;

typedef float f4 __attribute__((ext_vector_type(4)));

#define FEAT 64
#define CAP 32            // one 128B line per node row (avg deg 10)
#define OVF_CAP (1 << 20)
#define NT 256
#define NB 1024           // 4096 waves = 16/CU, co-resident

__global__ void __launch_bounds__(NT)
fused_kernel(const f4* __restrict__ mj4, const int* __restrict__ tgt,
             int* __restrict__ cursor, int* __restrict__ bucket,
             int* __restrict__ ovf_cnt, int* __restrict__ ovf,
             f4* __restrict__ out4, int E, int N) {
    cg::grid_group grid = cg::this_grid();
    int tid = blockIdx.x * NT + threadIdx.x;
    int nthr = gridDim.x * NT;

    // ---- phase 0: zero cursor + ovf_cnt (ovf_cnt sits at cursor[N]) ----
    for (int i = tid; i < N + 4; i += nthr) cursor[i] = 0;
    grid.sync();

    // ---- phase 1: scatter edge ids into per-node bucket rows ----
    for (int i = tid; i < E; i += nthr) {
        int t = tgt[i];
        int pos = atomicAdd(&cursor[t], 1);
        if (pos < CAP) {
            bucket[t * CAP + pos] = i;
        } else {                           // exact fallback, expected never
            int q = atomicAdd(ovf_cnt, 1);
            if (q < OVF_CAP) { ovf[2 * q] = t; ovf[2 * q + 1] = i; }
        }
    }
    __threadfence();   // agent-scope release: push bucket/cursor past XCD L2s
    grid.sync();

    // ---- phase 2: gather; 16-lane group per node, lane = float4 slot ----
    int l = tid & 15;
    int ngrp = nthr >> 4;
    int novf = *ovf_cnt;
    if (novf > OVF_CAP) novf = OVF_CAP;
    for (int gid = tid >> 4; gid < N; gid += ngrp) {
        int deg = cursor[gid];
        if (deg > CAP) deg = CAP;
        const int* row = bucket + gid * CAP;      // one 128B line
        const int4* row4 = (const int4*)row;      // 16B-aligned
        f4 acc = {0.f, 0.f, 0.f, 0.f};
        int j = 0;
        for (; j + 3 < deg; j += 4) {
            int4 ea = row4[j >> 2];
            f4 v0 = mj4[(size_t)ea.x * 16 + l];
            f4 v1 = mj4[(size_t)ea.y * 16 + l];
            f4 v2 = mj4[(size_t)ea.z * 16 + l];
            f4 v3 = mj4[(size_t)ea.w * 16 + l];
            acc += (v0 + v1) + (v2 + v3);
        }
        for (; j < deg; ++j) {
            acc += mj4[(size_t)row[j] * 16 + l];
        }
        if (novf > 0) {                           // exact, expected never taken
            for (int k = 0; k < novf; ++k) {
                if (ovf[2 * k] == gid) acc += mj4[(size_t)ovf[2 * k + 1] * 16 + l];
            }
        }
        out4[(size_t)gid * 16 + l] = acc;
    }
}

extern "C" void kernel_launch(void* const* d_in, const int* in_sizes, int n_in,
                              void* d_out, int out_size, void* d_ws, size_t ws_size,
                              hipStream_t stream) {
    const float* mj = (const float*)d_in[0];
    const int* edge_index = (const int*)d_in[1];  // [2, E] int32 row-major
    int E = in_sizes[1] / 2;
    const int* tgt_p = edge_index + E;            // row 1 = targets
    int N = out_size / FEAT;                      // 100,000

    int* cursor  = (int*)d_ws;                    // N
    int* ovf_cnt = cursor + N;                    // 1 (+3 pad)
    int* ovf     = cursor + N + 4;                // 2*OVF_CAP, 16B-aligned
    int* bucket  = ovf + 2 * OVF_CAP;             // N*CAP, 16B-aligned

    const f4* mj4 = (const f4*)mj;
    f4* out4 = (f4*)d_out;

    void* args[] = {(void*)&mj4, (void*)&tgt_p, (void*)&cursor, (void*)&bucket,
                    (void*)&ovf_cnt, (void*)&ovf, (void*)&out4,
                    (void*)&E, (void*)&N};
    hipLaunchCooperativeKernel((const void*)fused_kernel, dim3(NB), dim3(NT),
                               args, 0, stream);
}

// Round 8
// 122.144 us; speedup vs baseline: 3.3434x; 3.3434x over previous
//
#include <hip/hip_runtime.h>

// segment_sum via fixed-stride bucketing + gather, exact overflow fold.
// E = 1M edges, D = 64 f32 features, N = 100K nodes.
// R7: consolidation. R4's scatter + gather (best measured) with cleanup
// folded into gather (novf==0 fast path is one cached scalar load).
// 3 dispatches: memset(400KB) -> scatter -> gather.
// No NT hints (R3 lesson), no cooperative fusion (R6 lesson: co-residency
// halves TLP and grid.sync fencing across XCDs kills it).
//
// ws ints: cursor[N] | ovf_cnt(+3 pad) | ovf[2*OVF_CAP] | bucket[N*CAP]

typedef float f4 __attribute__((ext_vector_type(4)));

#define FEAT 64
#define CAP 32            // one 128B line per node row (avg deg 10)
#define OVF_CAP (1 << 20)

__global__ void __launch_bounds__(256)
scatter_kernel(const int* __restrict__ tgt, int* __restrict__ cursor,
               int* __restrict__ bucket, int* __restrict__ ovf_cnt,
               int* __restrict__ ovf, int E) {
    int i = blockIdx.x * 256 + threadIdx.x;
    if (i >= E) return;
    int t = tgt[i];
    int pos = atomicAdd(&cursor[t], 1);
    if (pos < CAP) {
        bucket[t * CAP + pos] = i;    // plain store: L2 coalesces the region
    } else {                          // exact fallback, expected never
        int q = atomicAdd(ovf_cnt, 1);
        if (q < OVF_CAP) { ovf[2 * q] = t; ovf[2 * q + 1] = i; }
    }
}

// 16-lane group per node; lane = float4 slot; 4 rows in flight per group
__global__ void __launch_bounds__(256)
gather_kernel(const f4* __restrict__ mj4, const int* __restrict__ cursor,
              const int* __restrict__ bucket, const int* __restrict__ ovf_cnt,
              const int* __restrict__ ovf, f4* __restrict__ out4, int N) {
    int gid = (blockIdx.x * 256 + threadIdx.x) >> 4;
    int l = threadIdx.x & 15;
    if (gid >= N) return;
    int deg = cursor[gid];
    if (deg > CAP) deg = CAP;
    const int* row = bucket + gid * CAP;   // exactly one 128B line
    f4 acc = {0.f, 0.f, 0.f, 0.f};
    int j = 0;
    for (; j + 3 < deg; j += 4) {
        int e0 = row[j], e1 = row[j + 1], e2 = row[j + 2], e3 = row[j + 3];
        f4 a = mj4[(size_t)e0 * 16 + l];
        f4 b = mj4[(size_t)e1 * 16 + l];
        f4 c = mj4[(size_t)e2 * 16 + l];
        f4 d = mj4[(size_t)e3 * 16 + l];
        acc += (a + b) + (c + d);
    }
    for (; j < deg; ++j) {
        acc += mj4[(size_t)row[j] * 16 + l];
    }
    // exact overflow fold; novf==0 in practice -> one cached scalar load
    int novf = *ovf_cnt;
    if (novf > 0) {
        if (novf > OVF_CAP) novf = OVF_CAP;
        for (int k = 0; k < novf; ++k) {
            if (ovf[2 * k] == gid) acc += mj4[(size_t)ovf[2 * k + 1] * 16 + l];
        }
    }
    out4[(size_t)gid * 16 + l] = acc;
}

extern "C" void kernel_launch(void* const* d_in, const int* in_sizes, int n_in,
                              void* d_out, int out_size, void* d_ws, size_t ws_size,
                              hipStream_t stream) {
    const float* mj = (const float*)d_in[0];
    const int* edge_index = (const int*)d_in[1];  // [2, E] int32 row-major
    int E = in_sizes[1] / 2;
    const int* tgt = edge_index + E;              // row 1 = targets
    int N = out_size / FEAT;                      // 100,000

    int* cursor  = (int*)d_ws;                    // N
    int* ovf_cnt = cursor + N;                    // 1 (+3 pad)
    int* ovf     = cursor + N + 4;                // 2*OVF_CAP, 16B-aligned
    int* bucket  = ovf + 2 * OVF_CAP;             // N*CAP, 16B-aligned

    hipMemsetAsync(cursor, 0, (size_t)(N + 4) * sizeof(int), stream);

    int eblk = (E + 255) / 256;
    scatter_kernel<<<eblk, 256, 0, stream>>>(tgt, cursor, bucket, ovf_cnt, ovf, E);

    int gblk = (N * 16 + 255) / 256;
    gather_kernel<<<gblk, 256, 0, stream>>>(
        (const f4*)mj, cursor, bucket, ovf_cnt, ovf, (f4*)d_out, N);
}